// Round 1
// baseline (4464.281 us; speedup 1.0000x reference)
//
#include <hip/hip_runtime.h>
#include <hip/hip_bf16.h>

// SimpleBiGRU on MI355X.
// Both "directions" are forward-in-time GRU scans (batch-flip is identity),
// with weights (Wi_f,Wh_f,...) and (Wi_b,Wh_b,...).
//
// Decomposition: 8 units = (dir 0..1) x (batch-group 0..3, 16 rows each).
// Each unit is served by 32 persistent WGs, each owning 16 hidden columns.
// Per step: hg = h @ Wh via mfma_f32_16x16x32_bf16 with weights held in
// VGPRs; inter-WG sync via agent-scope atomic flag counters; h carried fp32
// in a double-buffered global buffer (only MFMA inputs rounded to bf16).

#define BB 64
#define TT 512
#define FF 256
#define HH 512
#define G3 1536
#define NSLICE 32   // WGs per unit
#define NUNIT 8
#define NWG (NSLICE * NUNIT)   // 256
#define NTHR 192               // 3 waves: one per gate (r, z, n)

typedef __attribute__((ext_vector_type(8))) short short8;  // 8 x bf16
typedef __attribute__((ext_vector_type(4))) float f32x4;

__device__ __forceinline__ unsigned short f2bf(float f) {
  union { float f; unsigned u; } x; x.f = f;
  unsigned r = (x.u + 0x7fffu + ((x.u >> 16) & 1u)) >> 16;  // RNE
  return (unsigned short)r;
}

__global__ __launch_bounds__(NTHR) void gru_fused(
    const float* __restrict__ data,
    const float* __restrict__ Wi_f, const float* __restrict__ bi_f,
    const float* __restrict__ Wh_f, const float* __restrict__ bhn_f,
    const float* __restrict__ Wi_b, const float* __restrict__ bi_b,
    const float* __restrict__ Wh_b, const float* __restrict__ bhn_b,
    float* __restrict__ out,
    unsigned long long* __restrict__ hbuf,  // [dir][buf][col 512][rowpair 32] (2 x f32 per u64)
    int* __restrict__ flags)                // [unit 8][TT]
{
  const int wg   = blockIdx.x;
  const int unit = wg & 7;      // wg%8 -> same-XCD grouping heuristic for a unit's 32 WGs
  const int s    = wg >> 3;     // column slice 0..31
  const int dir  = unit >> 2;
  const int bg   = unit & 3;
  const int tid  = threadIdx.x;
  const int wv   = tid >> 6;    // 0=r, 1=z, 2=n
  const int lane = tid & 63;
  const int l15  = lane & 15;
  const int lg   = lane >> 4;

  const float* Wi  = dir ? Wi_b  : Wi_f;
  const float* Wh  = dir ? Wh_b  : Wh_f;
  const float* bi  = dir ? bi_b  : bi_f;
  const float* bhn = dir ? bhn_b : bhn_f;

  // LDS: hA = h(t-1) in bf16, swizzled, rows 0..15 x cols 0..511 (byte = row*1024 + ((2*col)^((row&7)<<4)))
  __shared__ __align__(16) char hA[16 * 1024];
  __shared__ float hP[16][17];   // fp32 h(t-1) for this WG's own 16 columns (exact carry path)
  __shared__ float r_s[16][17];
  __shared__ float z_s[16][17];

  const int colT = s * 16 + l15;       // this lane's output column within H
  const int gcol = wv * HH + colT;     // column within 3H for this wave's gate

  // ---- load weight B-fragments into registers (one-time) ----
  // k-slot mapping k = ks*32 + lg*8 + j, identical for A and B => layout-safe.
  short8 whf[16];
#pragma unroll
  for (int ks = 0; ks < 16; ++ks) {
    short8 v;
#pragma unroll
    for (int j = 0; j < 8; ++j) v[j] = (short)f2bf(Wh[(ks * 32 + lg * 8 + j) * G3 + gcol]);
    whf[ks] = v;
  }
  short8 wif[8];
#pragma unroll
  for (int ks = 0; ks < 8; ++ks) {
    short8 v;
#pragma unroll
    for (int j = 0; j < 8; ++j) v[j] = (short)f2bf(Wi[(ks * 32 + lg * 8 + j) * G3 + gcol]);
    wif[ks] = v;
  }
  const float bic  = bi[gcol];
  const float bhnc = bhn[colT];

  int* myflags = flags + unit * TT;
  const float* xbase = data + (size_t)(bg * 16 + l15) * TT * FF;
  const int sw = (l15 & 7) << 4;

  for (int t = 0; t < TT; ++t) {
    const int ib = t & 1, ob = ib ^ 1;

    // ---- xg MFMAs first: independent of h, overlaps the barrier wait ----
    f32x4 accX = {0.f, 0.f, 0.f, 0.f};
    {
      const float* xrow = xbase + t * FF;
#pragma unroll
      for (int ks = 0; ks < 8; ++ks) {
        short8 a;
#pragma unroll
        for (int j = 0; j < 8; ++j) a[j] = (short)f2bf(xrow[ks * 32 + lg * 8 + j]);
        accX = __builtin_amdgcn_mfma_f32_16x16x32_bf16(a, wif[ks], accX, 0, 0, 0);
      }
    }

    // ---- wait for h(t-1) from all 32 WGs of this unit ----
    if (t > 0 && tid == 0) {
      while (__hip_atomic_load(&myflags[t - 1], __ATOMIC_RELAXED, __HIP_MEMORY_SCOPE_AGENT) < NSLICE) {
        __builtin_amdgcn_s_sleep(1);
      }
    }
    __syncthreads();   // also protects hA/hP against overwrite while stragglers read

    // ---- stage h(t-1): global fp32 (LLC, atomic loads bypass caches) -> LDS ----
    {
      const unsigned long long* hin = hbuf + (size_t)(dir * 2 + ib) * 512 * 32;
      for (int i = tid; i < 4096; i += NTHR) {
        int col = i >> 3;       // 0..511
        int pr  = i & 7;        // row pair within this bg's 16 rows
        unsigned long long v = __hip_atomic_load(
            (unsigned long long*)(hin + (size_t)col * 32 + bg * 8 + pr),
            __ATOMIC_RELAXED, __HIP_MEMORY_SCOPE_AGENT);
        union { unsigned u; float f; } lo, hi;
        lo.u = (unsigned)v; hi.u = (unsigned)(v >> 32);
        int r0 = pr * 2, r1 = r0 + 1;
        *(unsigned short*)(hA + r0 * 1024 + ((col * 2) ^ ((r0 & 7) << 4))) = f2bf(lo.f);
        *(unsigned short*)(hA + r1 * 1024 + ((col * 2) ^ ((r1 & 7) << 4))) = f2bf(hi.f);
        if ((col >> 4) == s) { hP[r0][col & 15] = lo.f; hP[r1][col & 15] = hi.f; }
      }
    }
    __syncthreads();

    // ---- hg MFMAs: A from LDS (swizzled b128 reads), B from registers ----
    f32x4 accH = {0.f, 0.f, 0.f, 0.f};
    {
      const char* arow = hA + l15 * 1024;
#pragma unroll
      for (int ks = 0; ks < 16; ++ks) {
        short8 a = *(const short8*)(arow + ((ks * 64 + lg * 16) ^ sw));
        accH = __builtin_amdgcn_mfma_f32_16x16x32_bf16(a, whf[ks], accH, 0, 0, 0);
      }
    }

    // ---- gates; C/D layout: col = lane&15, row = 4*(lane>>4)+reg (m89-verified) ----
    if (wv == 0) {
#pragma unroll
      for (int j = 0; j < 4; ++j) {
        float pre = accX[j] + accH[j] + bic;
        r_s[lg * 4 + j][l15] = 1.f / (1.f + __expf(-pre));
      }
    } else if (wv == 1) {
#pragma unroll
      for (int j = 0; j < 4; ++j) {
        float pre = accX[j] + accH[j] + bic;
        z_s[lg * 4 + j][l15] = 1.f / (1.f + __expf(-pre));
      }
    }
    __syncthreads();

    if (wv == 2) {
      float hv[4];
#pragma unroll
      for (int j = 0; j < 4; ++j) {
        int row = lg * 4 + j;
        float r  = r_s[row][l15];
        float z  = z_s[row][l15];
        float hp = hP[row][l15];
        float n  = tanhf(accX[j] + bic + r * (accH[j] + bhnc));
        hv[j] = (1.f - z) * n + z * hp;
        out[((size_t)(bg * 16 + row) * TT + t) * 1024 + dir * 512 + colT] = hv[j];
      }
      union { float f; unsigned u; } c0, c1, c2, c3;
      c0.f = hv[0]; c1.f = hv[1]; c2.f = hv[2]; c3.f = hv[3];
      unsigned long long p0 = (unsigned long long)c0.u | ((unsigned long long)c1.u << 32);
      unsigned long long p1 = (unsigned long long)c2.u | ((unsigned long long)c3.u << 32);
      unsigned long long* hout = hbuf + (size_t)(dir * 2 + ob) * 512 * 32;
      size_t bidx = (size_t)colT * 32 + bg * 8 + lg * 2;
      __hip_atomic_store(&hout[bidx],     p0, __ATOMIC_RELAXED, __HIP_MEMORY_SCOPE_AGENT);
      __hip_atomic_store(&hout[bidx + 1], p1, __ATOMIC_RELAXED, __HIP_MEMORY_SCOPE_AGENT);
      // drain this wave's stores (vmcnt is per-wave; covers all 64 lanes) before release
      asm volatile("s_waitcnt vmcnt(0)" ::: "memory");
      if (lane == 0)
        __hip_atomic_fetch_add(&myflags[t], 1, __ATOMIC_RELAXED, __HIP_MEMORY_SCOPE_AGENT);
    }
  }
}

extern "C" void kernel_launch(void* const* d_in, const int* in_sizes, int n_in,
                              void* d_out, int out_size, void* d_ws, size_t ws_size,
                              hipStream_t stream) {
  const float* data  = (const float*)d_in[0];
  const float* Wi_f  = (const float*)d_in[1];
  const float* bi_f  = (const float*)d_in[2];
  const float* Wh_f  = (const float*)d_in[3];
  const float* bhn_f = (const float*)d_in[4];
  const float* Wi_b  = (const float*)d_in[5];
  const float* bi_b  = (const float*)d_in[6];
  const float* Wh_b  = (const float*)d_in[7];
  const float* bhn_b = (const float*)d_in[8];
  float* out = (float*)d_out;

  // ws: [0, 512KB) h double buffers (fp32, col-major pairs); [512KB, +16KB) flags
  unsigned long long* hbuf = (unsigned long long*)d_ws;
  int* flags = (int*)((char*)d_ws + 524288);
  hipMemsetAsync(d_ws, 0, 524288 + 16384, stream);  // h0 = 0, flags = 0 (every call)

  gru_fused<<<NWG, NTHR, 0, stream>>>(data, Wi_f, bi_f, Wh_f, bhn_f,
                                      Wi_b, bi_b, Wh_b, bhn_b, out, hbuf, flags);
}